// Round 4
// baseline (104.454 us; speedup 1.0000x reference)
//
#include <hip/hip_runtime.h>
#include <hip/hip_cooperative_groups.h>
#include <math.h>

namespace cg = cooperative_groups;

#define SEQT 24
#define NSTEP 23
#define NTOK 66        // real tokens 0..65
#define NST 67         // slot-state alphabet incl. empty (66)

// One cooperative kernel, grid = 256 blocks x 256 threads (1 block/CU).
//   Phase T (blocks 0..65): per-token fp64 tables -> d_ws   [R3 k_tables body]
//   grid.sync()
//   Phase E (all blocks):   stage u/vnwT -> LDS, compute EL per block (fp64)
//   Phase M (all blocks):   wave0 scan || waves1-3 stage head tables; head
__global__ __launch_bounds__(256) void k_coop(
    const int* __restrict__ seqs, const int* __restrict__ query_tok,
    const float* __restrict__ embed,
    const float* __restrict__ wg_w1, const float* __restrict__ wg_b1,
    const float* __restrict__ wg_w2, const float* __restrict__ wg_b2,
    const float* __restrict__ eg_w1, const float* __restrict__ eg_b1,
    const float* __restrict__ eg_w2, const float* __restrict__ eg_b2,
    const float* __restrict__ rh_w1, const float* __restrict__ rh_b1,
    const float* __restrict__ rh_w2, const float* __restrict__ rh_b2,
    float* __restrict__ out,
    double* __restrict__ t_u,      // [66][32]
    double* __restrict__ t_vnwT,   // [32][67], col 66 = 0
    float*  __restrict__ t_qh1,    // [66][64]
    float*  __restrict__ t_ebw)    // [66][64]
{
    // LDS pool (~53 KB), phase-overlaid:
    //  sA: phaseE u[66][33] fp64      | phaseM qh1[66][64] fp32
    //  sB: phaseE vnwT[32][68] fp64   | phaseM ebw[67][64] fp32
    //  sEL: phaseT scratch (s_h/s_e/s_w) | EL[66][67] fp32
    __shared__ __align__(16) double sA[2178];
    __shared__ __align__(16) double sB[2176];
    __shared__ __align__(16) float  sEL[NTOK * NST];
    __shared__ int s_state[64];

    const int tid = threadIdx.x;
    cg::grid_group grid = cg::this_grid();

    // ---------------- Phase T: per-token tables (blocks 0..65) ----------------
    if (blockIdx.x < NTOK) {
        double* s_h = (double*)sEL;           // 32 dbl  (bytes 0..255)
        float*  s_e = (float*)(sEL + 128);    // 64 f32  (bytes 512..767)
        double* s_wp = (double*)(sEL + 300);  // 1 dbl   (byte 1200, 8-aligned)

        const int a = blockIdx.x;
        const int t = tid;
        if (t < 64) s_e[t] = embed[a * 64 + t];
        __syncthreads();

        const float* wp = nullptr;
        int stride = 32, col = 0;
        if      (t < 32)  { wp = eg_w1;            col = t;       }
        else if (t < 64)  { wp = eg_w1 + 64 * 32;  col = t - 32;  }
        else if (t < 96)  { wp = wg_w1;            col = t - 64;  }
        else if (t < 160) { wp = rh_w1;            col = t - 96;  stride = 64; }
        else if (t < 224) { wp = rh_w1 + 64 * 64;  col = t - 160; stride = 64; }

        double acc = 0.0;
        if (t < 224) {
            #pragma unroll 8
            for (int k = 0; k < 64; ++k)
                acc += (double)s_e[k] * (double)wp[k * stride + col];
        }

        if (t >= 64 && t < 96) {
            const int j = t - 64;
            double hr = acc + (double)wg_b1[j];
            if (hr < 0.0) hr = 0.0;
            s_h[j] = hr * (double)wg_w2[j];
        }
        __syncthreads();
        if (t == 0) {
            double z = (double)wg_b2[0];
            for (int j = 0; j < 32; ++j) z += s_h[j];
            s_wp[0] = 1.0 / (1.0 + exp(-z));
        }
        __syncthreads();
        const double w = s_wp[0];

        if      (t < 32)  { t_u[a * 32 + t] = acc + (double)eg_b1[t];
                            if (a == 0) t_vnwT[t * NST + 66] = 0.0; }   // empty col
        else if (t < 64)  { t_vnwT[col * NST + a] = w * acc; }
        else if (t >= 96 && t < 160)  { t_qh1[a * 64 + col] = (float)(acc + (double)rh_b1[col]); }
        else if (t >= 160 && t < 224) { t_ebw[a * 64 + col] = (float)(0.25 * w * acc); }
        __threadfence();   // make table writes device-visible before the barrier
    }

    grid.sync();

    // ---------------- Phase E: per-block EL table ----------------
    // stage u (2112 dbl) padded to stride 33; vnwT (2144 dbl) padded to stride 68
    for (int i = tid; i < NTOK * 32; i += 256)
        sA[(i >> 5) * 33 + (i & 31)] = t_u[i];
    for (int i = tid; i < 32 * NST; i += 256) {
        const int j = i / NST, b = i - j * NST;
        sB[j * 68 + b] = t_vnwT[i];
    }
    __syncthreads();

    const double eb2 = (double)eg_b2[0];
    for (int it = tid; it < NTOK * NST; it += 256) {
        const int a = it / NST, b = it - a * NST;
        double acc = eb2;
        #pragma unroll
        for (int j = 0; j < 32; ++j) {
            const double v = sA[a * 33 + j] + sB[j * 68 + b];
            if (v > 0.0) acc += v * (double)eg_w2[j];   // same order as verified k_el
        }
        sEL[it] = (float)acc;
    }
    __syncthreads();

    // ---------------- Phase M: scan + head ----------------
    float* s_qh1 = (float*)sA;    // [66][64]
    float* s_ebw = (float*)sB;    // [67][64], row 66 = 0

    const int wv = tid >> 6, lane = tid & 63;

    if (wv == 0) {
        // scan: one batch element per lane
        const int b = blockIdx.x * 64 + lane;
        const int4* rp = (const int4*)(seqs + b * SEQT);   // 96B-aligned rows
        const int4 q0 = rp[0], q1 = rp[1], q2 = rp[2], q3 = rp[3], q4 = rp[4], q5 = rp[5];
        int row[24];
        row[0]=q0.x;  row[1]=q0.y;  row[2]=q0.z;  row[3]=q0.w;
        row[4]=q1.x;  row[5]=q1.y;  row[6]=q1.z;  row[7]=q1.w;
        row[8]=q2.x;  row[9]=q2.y;  row[10]=q2.z; row[11]=q2.w;
        row[12]=q3.x; row[13]=q3.y; row[14]=q3.z; row[15]=q3.w;
        row[16]=q4.x; row[17]=q4.y; row[18]=q4.z; row[19]=q4.w;
        row[20]=q5.x; row[21]=q5.y; row[22]=q5.z; row[23]=q5.w;

        int ts0 = 66, ts1 = 66, ts2 = 66, ts3 = 66;
        #pragma unroll
        for (int t = 0; t < NSTEP; ++t) {
            const int tok  = row[t];            // static after full unroll
            const int base = tok * NST;
            const float e0 = sEL[base + ts0];
            const float e1 = sEL[base + ts1];
            const float e2 = sEL[base + ts2];
            const float e3 = sEL[base + ts3];
            int bi = 0; float best = e0;        // first-of-max == jnp.argmax
            if (e1 > best) { best = e1; bi = 1; }
            if (e2 > best) { best = e2; bi = 2; }
            if (e3 > best) { best = e3; bi = 3; }
            ts0 = (bi == 0) ? tok : ts0;
            ts1 = (bi == 1) ? tok : ts1;
            ts2 = (bi == 2) ? tok : ts2;
            ts3 = (bi == 3) ? tok : ts3;
        }
        s_state[lane] = ts0 | (ts1 << 8) | (ts2 << 16) | (ts3 << 24);
    } else {
        // waves 1-3: stage qh1 + ebw as float4 (2112 vec4s / 192 threads)
        const float4* gq = (const float4*)t_qh1;   // 1056 vec4
        const float4* ge = (const float4*)t_ebw;   // 1056 vec4
        float4* sq = (float4*)s_qh1;
        float4* se = (float4*)s_ebw;
        for (int i = tid - 64; i < 2112; i += 192) {
            if (i < 1056) sq[i] = gq[i];
            else          se[i - 1056] = ge[i - 1056];
        }
        if (tid < 128) s_ebw[NTOK * 64 + (tid - 64)] = 0.0f;   // empty-slot row 66
    }
    __syncthreads();

    // head: per-lane-resident rh_w2 column, 16 elems per wave
    float w2c[64];                              // lane o holds rh_w2[:, o]
    #pragma unroll
    for (int k = 0; k < 64; ++k) w2c[k] = rh_w2[k * 64 + lane];
    const float rb2 = rh_b2[lane];

    for (int i = 0; i < 16; ++i) {
        const int e  = wv * 16 + i;
        const int bg = blockIdx.x * 64 + e;
        const int qt = query_tok[bg];
        const unsigned st = (unsigned)s_state[e];
        const int u0 = st & 255, u1 = (st >> 8) & 255,
                  u2 = (st >> 16) & 255, u3 = st >> 24;
        float h1 = s_qh1[qt * 64 + lane]
                 + s_ebw[u0 * 64 + lane] + s_ebw[u1 * 64 + lane]
                 + s_ebw[u2 * 64 + lane] + s_ebw[u3 * 64 + lane];
        h1 = fmaxf(h1, 0.0f);

        float a0 = rb2, a1 = 0.0f, a2 = 0.0f, a3 = 0.0f;
        #pragma unroll
        for (int k = 0; k < 64; k += 4) {
            const float h0 = __uint_as_float(__builtin_amdgcn_readlane(__float_as_uint(h1), k));
            const float hA = __uint_as_float(__builtin_amdgcn_readlane(__float_as_uint(h1), k + 1));
            const float hB = __uint_as_float(__builtin_amdgcn_readlane(__float_as_uint(h1), k + 2));
            const float hC = __uint_as_float(__builtin_amdgcn_readlane(__float_as_uint(h1), k + 3));
            a0 = fmaf(h0, w2c[k],     a0);
            a1 = fmaf(hA, w2c[k + 1], a1);
            a2 = fmaf(hB, w2c[k + 2], a2);
            a3 = fmaf(hC, w2c[k + 3], a3);
        }
        out[bg * 64 + lane] = (a0 + a1) + (a2 + a3);
    }
}

extern "C" void kernel_launch(void* const* d_in, const int* in_sizes, int n_in,
                              void* d_out, int out_size, void* d_ws, size_t ws_size,
                              hipStream_t stream)
{
    const int*   seqs      = (const int*)  d_in[0];
    const int*   query_tok = (const int*)  d_in[1];
    const float* embed     = (const float*)d_in[2];
    const float* wg_w1     = (const float*)d_in[3];
    const float* wg_b1     = (const float*)d_in[4];
    const float* wg_w2     = (const float*)d_in[5];
    const float* wg_b2     = (const float*)d_in[6];
    const float* eg_w1     = (const float*)d_in[7];
    const float* eg_b1     = (const float*)d_in[8];
    const float* eg_w2     = (const float*)d_in[9];
    const float* eg_b2     = (const float*)d_in[10];
    const float* rh_w1     = (const float*)d_in[11];
    const float* rh_b1     = (const float*)d_in[12];
    const float* rh_w2     = (const float*)d_in[13];
    const float* rh_b2     = (const float*)d_in[14];
    float* out = (float*)d_out;
    const int B = in_sizes[1];   // 16384

    double* t_u    = (double*)d_ws;                    // 66*32 fp64
    double* t_vnwT = t_u + NTOK * 32;                  // 32*67 fp64
    float*  t_qh1  = (float*)(t_vnwT + 32 * NST);      // 66*64 fp32
    float*  t_ebw  = t_qh1 + NTOK * 64;                // 66*64 fp32

    void* kargs[] = {
        (void*)&seqs, (void*)&query_tok, (void*)&embed,
        (void*)&wg_w1, (void*)&wg_b1, (void*)&wg_w2, (void*)&wg_b2,
        (void*)&eg_w1, (void*)&eg_b1, (void*)&eg_w2, (void*)&eg_b2,
        (void*)&rh_w1, (void*)&rh_b1, (void*)&rh_w2, (void*)&rh_b2,
        (void*)&out, (void*)&t_u, (void*)&t_vnwT, (void*)&t_qh1, (void*)&t_ebw
    };
    hipLaunchCooperativeKernel((void*)k_coop, dim3(B / 64), dim3(256),
                               kargs, 0, stream);
}

// Round 5
// 38.733 us; speedup vs baseline: 2.6968x; 2.6968x over previous
//
#include <hip/hip_runtime.h>
#include <math.h>

#define SEQT 24
#define NSTEP 23
#define NTOK 66        // real tokens 0..65
#define NST 67         // slot-state alphabet incl. empty (66)
#define NB 32          // batch elems per k_main block

// ---------------- K1: tables + EL column-slices, 11 blocks x 256 ----------------
// Block i owns token/state slice [6i, 6i+6). It computes:
//   - u[a][j] for ALL a (redundant base, 2112 dots)  -> LDS
//   - nb, wg-partials, qh1-raw, ebw-raw for OWN slice (1152 dots) -> LDS
//   - w(b) for own slice; EL[a][b] for own columns (block 10 also col 66)
//   - t_qh1/t_ebw rows for own slice
// All fp64 dot accumulations are sequential in k (0..63) and EL in j (0..31),
// matching the verified R3 numerics bit-for-bit; ILP comes from 4 independent
// dot chains per thread, never from splitting a single dot.
__global__ __launch_bounds__(256) void k_tables(
    const float* __restrict__ embed,
    const float* __restrict__ wg_w1, const float* __restrict__ wg_b1,
    const float* __restrict__ wg_w2, const float* __restrict__ wg_b2,
    const float* __restrict__ eg_w1, const float* __restrict__ eg_b1,
    const float* __restrict__ eg_w2, const float* __restrict__ eg_b2,
    const float* __restrict__ rh_w1, const float* __restrict__ rh_b1,
    float* __restrict__ t_EL,    // [66][67]
    float* __restrict__ t_qh1,   // [66][64]
    float* __restrict__ t_ebw)   // [66][64]
{
    __shared__ __align__(16) float s_emb[NTOK * 64];  // 16.9 KB
    __shared__ double s_u[NTOK][33];                  // 17.4 KB (pad 33: bank spread)
    __shared__ double s_nb[6][33];
    __shared__ double s_h[6][33];
    __shared__ double s_wnb[7][33];                   // row 6 = zeros (empty state)
    __shared__ double s_qraw[6 * 64];
    __shared__ double s_ebraw[6 * 64];
    __shared__ double s_w[6];

    const int tid = threadIdx.x;
    const int blk = blockIdx.x;
    const int b0  = blk * 6;

    // stage embed -> LDS (vec4)
    {
        const float4* ge = (const float4*)embed;      // 1056 vec4
        float4* se = (float4*)s_emb;
        for (int i = tid; i < 1056; i += 256) se[i] = ge[i];
    }
    __syncthreads();

    // ---- dot phase: 3264 dots, 4-chain ILP ----
    // d in [0,2112):    u     a=d>>5, j=d&31        (eg_w1 top)
    // d in [2112,2304): nb    r=(d-2112)>>5, j      (eg_w1 bot)
    // d in [2304,2496): wg    r, j                  (wg_w1)
    // d in [2496,2880): qh1   r=(d-2496)>>6, c&63   (rh_w1 top)
    // d in [2880,3264): ebw   r, c                  (rh_w1 bot)
    for (int base = 0; base < 3264; base += 1024) {
        const float* wp[4]; int st[4], col[4], er[4], dd[4]; bool act[4];
        #pragma unroll
        for (int m = 0; m < 4; ++m) {
            int d = base + tid + m * 256;
            act[m] = d < 3264; dd[m] = d;
            int dc = act[m] ? d : 0;
            if (dc < 2112)      { wp[m] = eg_w1;           st[m] = 32; col[m] = dc & 31; er[m] = dc >> 5; }
            else if (dc < 2304) { int x = dc - 2112; wp[m] = eg_w1 + 64 * 32; st[m] = 32; col[m] = x & 31; er[m] = b0 + (x >> 5); }
            else if (dc < 2496) { int x = dc - 2304; wp[m] = wg_w1;           st[m] = 32; col[m] = x & 31; er[m] = b0 + (x >> 5); }
            else if (dc < 2880) { int x = dc - 2496; wp[m] = rh_w1;           st[m] = 64; col[m] = x & 63; er[m] = b0 + (x >> 6); }
            else                { int x = dc - 2880; wp[m] = rh_w1 + 64 * 64; st[m] = 64; col[m] = x & 63; er[m] = b0 + (x >> 6); }
        }
        double acc[4] = {0.0, 0.0, 0.0, 0.0};
        #pragma unroll 8
        for (int k = 0; k < 64; ++k) {
            #pragma unroll
            for (int m = 0; m < 4; ++m)
                acc[m] += (double)s_emb[er[m] * 64 + k] * (double)wp[m][k * st[m] + col[m]];
        }
        #pragma unroll
        for (int m = 0; m < 4; ++m) {
            if (!act[m]) continue;
            const int d = dd[m];
            if (d < 2112) {
                s_u[d >> 5][d & 31] = acc[m] + (double)eg_b1[d & 31];
            } else if (d < 2304) {
                const int x = d - 2112; s_nb[x >> 5][x & 31] = acc[m];
            } else if (d < 2496) {
                const int x = d - 2304, j = x & 31;
                double hr = acc[m] + (double)wg_b1[j];
                if (hr < 0.0) hr = 0.0;
                s_h[x >> 5][j] = hr * (double)wg_w2[j];
            } else if (d < 2880) {
                s_qraw[d - 2496] = acc[m];
            } else {
                s_ebraw[d - 2880] = acc[m];
            }
        }
    }
    __syncthreads();

    // ---- write gate (own slice) ----
    if (tid < 6) {
        double z = (double)wg_b2[0];
        #pragma unroll
        for (int j = 0; j < 32; ++j) z += s_h[tid][j];
        s_w[tid] = 1.0 / (1.0 + exp(-z));
    }
    __syncthreads();

    // ---- wnb = w*nb (once per (r,j), same product as verified t_vnwT) ;
    //      finalize qh1/ebw rows ----
    if (tid < 224) {
        const int r = tid >> 5, j = tid & 31;
        s_wnb[r][j] = (r < 6) ? s_w[r] * s_nb[r][j] : 0.0;   // row 6 = empty state
    }
    for (int x = tid; x < 384; x += 256) {
        const int r = x >> 6, c = x & 63;
        t_qh1[(b0 + r) * 64 + c] = (float)(s_qraw[x] + (double)rh_b1[c]);
        t_ebw[(b0 + r) * 64 + c] = (float)(0.25 * s_w[r] * s_ebraw[x]);
    }
    __syncthreads();

    // ---- EL columns: all a, own cols (block 10 also col 66 via wnb row 6) ----
    const int ncol = (blk == 10) ? 7 : 6;
    const double eb2 = (double)eg_b2[0];
    for (int it = tid; it < NTOK * ncol; it += 256) {
        const int a = it / ncol, r = it - a * ncol;
        double acc = eb2;
        #pragma unroll
        for (int j = 0; j < 32; ++j) {
            const double v = s_u[a][j] + s_wnb[r][j];
            if (v > 0.0) acc += v * (double)eg_w2[j];
        }
        t_EL[a * NST + (b0 + r)] = (float)acc;
    }
}

// ---------------- K2: fused scan + head, 32 batch elems per block ----------------
__global__ __launch_bounds__(256) void k_main(
    const int* __restrict__ seqs, const int* __restrict__ query_tok,
    const float* __restrict__ t_EL, const float* __restrict__ t_qh1,
    const float* __restrict__ t_ebw,
    const float* __restrict__ rh_w2, const float* __restrict__ rh_b2,
    float* __restrict__ out)
{
    __shared__ __align__(16) float sEL[NTOK * NST];   // 17.7 KB
    __shared__ __align__(16) float s_qh1[NTOK * 64];  // 16.9 KB
    __shared__ __align__(16) float s_ebw[NST * 64];   // 17.2 KB
    __shared__ int s_state[NB];

    const int tid = threadIdx.x;
    const int wv = tid >> 6, lane = tid & 63;

    // wave0 scan lanes: issue seqs loads first (hide HBM latency under staging)
    int4 q0, q1, q2, q3, q4, q5;
    if (wv == 0 && lane < NB) {
        const int4* rp = (const int4*)(seqs + (blockIdx.x * NB + lane) * SEQT);
        q0 = rp[0]; q1 = rp[1]; q2 = rp[2]; q3 = rp[3]; q4 = rp[4]; q5 = rp[5];
    }

    // stage EL (all 256 threads): 1105 vec4 + 2 tail floats
    {
        const float4* g4 = (const float4*)t_EL;
        float4* s4 = (float4*)sEL;
        for (int i = tid; i < 1105; i += 256) s4[i] = g4[i];
        if (tid < 2) sEL[4420 + tid] = t_EL[4420 + tid];
    }
    __syncthreads();

    if (wv == 0) {
        if (lane < NB) {
            int row[24];
            row[0]=q0.x;  row[1]=q0.y;  row[2]=q0.z;  row[3]=q0.w;
            row[4]=q1.x;  row[5]=q1.y;  row[6]=q1.z;  row[7]=q1.w;
            row[8]=q2.x;  row[9]=q2.y;  row[10]=q2.z; row[11]=q2.w;
            row[12]=q3.x; row[13]=q3.y; row[14]=q3.z; row[15]=q3.w;
            row[16]=q4.x; row[17]=q4.y; row[18]=q4.z; row[19]=q4.w;
            row[20]=q5.x; row[21]=q5.y; row[22]=q5.z; row[23]=q5.w;

            int ts0 = 66, ts1 = 66, ts2 = 66, ts3 = 66;
            #pragma unroll
            for (int t = 0; t < NSTEP; ++t) {
                const int tok  = row[t];            // static after full unroll
                const int base = tok * NST;
                const float e0 = sEL[base + ts0];
                const float e1 = sEL[base + ts1];
                const float e2 = sEL[base + ts2];
                const float e3 = sEL[base + ts3];
                int bi = 0; float best = e0;        // first-of-max == jnp.argmax
                if (e1 > best) { best = e1; bi = 1; }
                if (e2 > best) { best = e2; bi = 2; }
                if (e3 > best) { best = e3; bi = 3; }
                ts0 = (bi == 0) ? tok : ts0;
                ts1 = (bi == 1) ? tok : ts1;
                ts2 = (bi == 2) ? tok : ts2;
                ts3 = (bi == 3) ? tok : ts3;
            }
            s_state[lane] = ts0 | (ts1 << 8) | (ts2 << 16) | (ts3 << 24);
        }
    } else {
        // waves 1-3: stage qh1 + ebw as float4 (2112 vec4s / 192 threads)
        const float4* gq = (const float4*)t_qh1;   // 1056 vec4
        const float4* ge = (const float4*)t_ebw;   // 1056 vec4
        float4* sq = (float4*)s_qh1;
        float4* se = (float4*)s_ebw;
        for (int i = tid - 64; i < 2112; i += 192) {
            if (i < 1056) sq[i] = gq[i];
            else          se[i - 1056] = ge[i - 1056];
        }
        if (tid < 128) s_ebw[NTOK * 64 + (tid - 64)] = 0.0f;   // empty-slot row 66
    }
    __syncthreads();

    // head: per-lane-resident rh_w2 column, 8 elems per wave
    float w2c[64];                              // lane o holds rh_w2[:, o]
    #pragma unroll
    for (int k = 0; k < 64; ++k) w2c[k] = rh_w2[k * 64 + lane];
    const float rb2 = rh_b2[lane];

    for (int i = 0; i < 8; ++i) {
        const int e  = wv * 8 + i;
        const int bg = blockIdx.x * NB + e;
        const int qt = query_tok[bg];
        const unsigned st = (unsigned)s_state[e];
        const int u0 = st & 255, u1 = (st >> 8) & 255,
                  u2 = (st >> 16) & 255, u3 = st >> 24;
        float h1 = s_qh1[qt * 64 + lane]
                 + s_ebw[u0 * 64 + lane] + s_ebw[u1 * 64 + lane]
                 + s_ebw[u2 * 64 + lane] + s_ebw[u3 * 64 + lane];
        h1 = fmaxf(h1, 0.0f);

        float a0 = rb2, a1 = 0.0f, a2 = 0.0f, a3 = 0.0f;
        #pragma unroll
        for (int k = 0; k < 64; k += 4) {
            const float h0 = __uint_as_float(__builtin_amdgcn_readlane(__float_as_uint(h1), k));
            const float hA = __uint_as_float(__builtin_amdgcn_readlane(__float_as_uint(h1), k + 1));
            const float hB = __uint_as_float(__builtin_amdgcn_readlane(__float_as_uint(h1), k + 2));
            const float hC = __uint_as_float(__builtin_amdgcn_readlane(__float_as_uint(h1), k + 3));
            a0 = fmaf(h0, w2c[k],     a0);
            a1 = fmaf(hA, w2c[k + 1], a1);
            a2 = fmaf(hB, w2c[k + 2], a2);
            a3 = fmaf(hC, w2c[k + 3], a3);
        }
        out[bg * 64 + lane] = (a0 + a1) + (a2 + a3);
    }
}

extern "C" void kernel_launch(void* const* d_in, const int* in_sizes, int n_in,
                              void* d_out, int out_size, void* d_ws, size_t ws_size,
                              hipStream_t stream)
{
    const int*   seqs      = (const int*)  d_in[0];
    const int*   query_tok = (const int*)  d_in[1];
    const float* embed     = (const float*)d_in[2];
    const float* wg_w1     = (const float*)d_in[3];
    const float* wg_b1     = (const float*)d_in[4];
    const float* wg_w2     = (const float*)d_in[5];
    const float* wg_b2     = (const float*)d_in[6];
    const float* eg_w1     = (const float*)d_in[7];
    const float* eg_b1     = (const float*)d_in[8];
    const float* eg_w2     = (const float*)d_in[9];
    const float* eg_b2     = (const float*)d_in[10];
    const float* rh_w1     = (const float*)d_in[11];
    const float* rh_b1     = (const float*)d_in[12];
    const float* rh_w2     = (const float*)d_in[13];
    const float* rh_b2     = (const float*)d_in[14];
    float* out = (float*)d_out;
    const int B = in_sizes[1];   // 16384

    // workspace: t_EL padded to 4432 floats so t_qh1/t_ebw stay 16B-aligned
    float* t_EL  = (float*)d_ws;          // 66*67 used (4432 reserved)
    float* t_qh1 = t_EL + 4432;           // 66*64
    float* t_ebw = t_qh1 + 4224;          // 66*64

    k_tables<<<11, 256, 0, stream>>>(embed, wg_w1, wg_b1, wg_w2, wg_b2,
                                     eg_w1, eg_b1, eg_w2, eg_b2,
                                     rh_w1, rh_b1, t_EL, t_qh1, t_ebw);
    k_main<<<B / NB, 256, 0, stream>>>(seqs, query_tok, t_EL, t_qh1, t_ebw,
                                       rh_w2, rh_b2, out);
}

// Round 6
// 29.321 us; speedup vs baseline: 3.5624x; 1.3210x over previous
//
#include <hip/hip_runtime.h>
#include <math.h>

#define SEQT 24
#define NSTEP 23
#define NTOK 66        // real tokens 0..65
#define NST 67         // slot-state alphabet incl. empty (66)
#define NB 64          // batch elems per k_main block

// ---------------- K1: tables + one EL column per block (66 blocks x 256) ----
// Block a computes:
//   - u[x][j] for ALL x (redundant, 8 uniform chains/thread, shared wt load)
//   - own-token nb/wg/qh1/ebw (1 mixed dot/thread, 192 active)
//   - w(a) sigmoid; wnb[j] = w(a)*nb[j] in LDS
//   - EL[x][a] for all x (block 65 also column 66 with wnb = 0)
// All per-dot k-order and EL j-order match the verified R3 numerics exactly.
__global__ __launch_bounds__(256) void k_tables(
    const float* __restrict__ embed,
    const float* __restrict__ wg_w1, const float* __restrict__ wg_b1,
    const float* __restrict__ wg_w2, const float* __restrict__ wg_b2,
    const float* __restrict__ eg_w1, const float* __restrict__ eg_b1,
    const float* __restrict__ eg_w2, const float* __restrict__ eg_b2,
    const float* __restrict__ rh_w1, const float* __restrict__ rh_b1,
    float* __restrict__ t_EL,    // [66][67]
    float* __restrict__ t_qh1,   // [66][64]
    float* __restrict__ t_ebw)   // [66][64]
{
    __shared__ __align__(16) float s_emb[NTOK * 64];  // 16.9 KB
    __shared__ double s_u[NTOK][33];                  // 17.4 KB (pad: bank spread)
    __shared__ double s_wnb[32];
    __shared__ double s_h[32];
    __shared__ double s_w;

    const int tid = threadIdx.x;
    const int a   = blockIdx.x;
    const int j     = tid & 31;
    const int rbase = tid >> 5;   // 0..7

    // stage embed -> LDS (vec4)
    {
        const float4* ge = (const float4*)embed;      // 1056 vec4
        float4* se = (float4*)s_emb;
        for (int i = tid; i < 1056; i += 256) se[i] = ge[i];
    }
    __syncthreads();

    // ---- phase A: u-rows 0..63, 8 chains/thread, one weight load per k ----
    {
        double acc[8] = {0.0, 0.0, 0.0, 0.0, 0.0, 0.0, 0.0, 0.0};
        #pragma unroll 4
        for (int k = 0; k < 64; ++k) {
            const double wv = (double)eg_w1[k * 32 + j];
            #pragma unroll
            for (int m = 0; m < 8; ++m)
                acc[m] += (double)s_emb[(rbase + 8 * m) * 64 + k] * wv;
        }
        #pragma unroll
        for (int m = 0; m < 8; ++m)
            s_u[rbase + 8 * m][j] = acc[m] + (double)eg_b1[j];
    }

    // ---- phase B: mixed dots (u rows 64-65; own nb/wg/qh1/ebw) ----
    const float* wp; int col, er, mode, stride;
    if      (tid < 64)  { mode = 0; er = 64 + rbase - 0; er = 64 + (tid >> 5); col = j;         wp = eg_w1;           stride = 32; }
    else if (tid < 96)  { mode = 1; er = a;              col = tid - 64;       wp = eg_w1 + 64 * 32; stride = 32; }
    else if (tid < 128) { mode = 2; er = a;              col = tid - 96;       wp = wg_w1;           stride = 32; }
    else if (tid < 192) { mode = 3; er = a;              col = tid - 128;      wp = rh_w1;           stride = 64; }
    else                { mode = 4; er = a;              col = tid - 192;      wp = rh_w1 + 64 * 64; stride = 64; }

    double accm = 0.0;
    #pragma unroll 8
    for (int k = 0; k < 64; ++k)
        accm += (double)s_emb[er * 64 + k] * (double)wp[k * stride + col];

    if (mode == 0) s_u[er][col] = accm + (double)eg_b1[col];
    if (mode == 2) {
        double hr = accm + (double)wg_b1[col];
        if (hr < 0.0) hr = 0.0;
        s_h[col] = hr * (double)wg_w2[col];
    }
    __syncthreads();
    if (tid == 0) {
        double z = (double)wg_b2[0];
        for (int jj = 0; jj < 32; ++jj) z += s_h[jj];
        s_w = 1.0 / (1.0 + exp(-z));
    }
    __syncthreads();
    const double w = s_w;
    if (mode == 1) s_wnb[col] = w * accm;                               // own wnb col
    if (mode == 3) t_qh1[a * 64 + col] = (float)(accm + (double)rh_b1[col]);
    if (mode == 4) t_ebw[a * 64 + col] = (float)(0.25 * w * accm);
    __syncthreads();

    // ---- EL column a (all x); block 65 also empty-state column 66 ----
    const double eb2 = (double)eg_b2[0];
    for (int x = tid; x < NTOK; x += 256) {
        double acc = eb2;
        #pragma unroll
        for (int jj = 0; jj < 32; ++jj) {
            const double v = s_u[x][jj] + s_wnb[jj];
            if (v > 0.0) acc += v * (double)eg_w2[jj];
        }
        t_EL[x * NST + a] = (float)acc;
    }
    if (a == NTOK - 1) {
        for (int x = tid; x < NTOK; x += 256) {
            double acc = eb2;
            #pragma unroll
            for (int jj = 0; jj < 32; ++jj) {
                const double v = s_u[x][jj] + 0.0;   // empty state: wnb = 0
                if (v > 0.0) acc += v * (double)eg_w2[jj];
            }
            t_EL[x * NST + 66] = (float)acc;
        }
    }
}

// ---------------- K2: fused scan + head, 64 batch elems per block (R3 verbatim) --
__global__ __launch_bounds__(256) void k_main(
    const int* __restrict__ seqs, const int* __restrict__ query_tok,
    const float* __restrict__ t_EL, const float* __restrict__ t_qh1,
    const float* __restrict__ t_ebw,
    const float* __restrict__ rh_w2, const float* __restrict__ rh_b2,
    float* __restrict__ out)
{
    __shared__ __align__(16) float sEL[NTOK * NST];   // 17.7 KB
    __shared__ __align__(16) float s_qh1[NTOK * 64];  // 16.9 KB
    __shared__ __align__(16) float s_ebw[NST * 64];   // 17.2 KB
    __shared__ int s_state[NB];

    const int tid = threadIdx.x;

    // stage EL (all 256 threads): 1105 vec4 + 2 tail floats
    {
        const float4* g4 = (const float4*)t_EL;
        float4* s4 = (float4*)sEL;
        for (int i = tid; i < 1105; i += 256) s4[i] = g4[i];
        if (tid < 2) sEL[4420 + tid] = t_EL[4420 + tid];
    }
    __syncthreads();

    const int wv = tid >> 6, lane = tid & 63;

    if (wv == 0) {
        // scan: one batch element per lane
        const int b = blockIdx.x * NB + lane;
        const int4* rp = (const int4*)(seqs + b * SEQT);   // 96B-aligned rows
        const int4 q0 = rp[0], q1 = rp[1], q2 = rp[2], q3 = rp[3], q4 = rp[4], q5 = rp[5];
        int row[24];
        row[0]=q0.x;  row[1]=q0.y;  row[2]=q0.z;  row[3]=q0.w;
        row[4]=q1.x;  row[5]=q1.y;  row[6]=q1.z;  row[7]=q1.w;
        row[8]=q2.x;  row[9]=q2.y;  row[10]=q2.z; row[11]=q2.w;
        row[12]=q3.x; row[13]=q3.y; row[14]=q3.z; row[15]=q3.w;
        row[16]=q4.x; row[17]=q4.y; row[18]=q4.z; row[19]=q4.w;
        row[20]=q5.x; row[21]=q5.y; row[22]=q5.z; row[23]=q5.w;

        int ts0 = 66, ts1 = 66, ts2 = 66, ts3 = 66;
        #pragma unroll
        for (int t = 0; t < NSTEP; ++t) {
            const int tok  = row[t];            // static after full unroll
            const int base = tok * NST;
            const float e0 = sEL[base + ts0];
            const float e1 = sEL[base + ts1];
            const float e2 = sEL[base + ts2];
            const float e3 = sEL[base + ts3];
            int bi = 0; float best = e0;        // first-of-max == jnp.argmax
            if (e1 > best) { best = e1; bi = 1; }
            if (e2 > best) { best = e2; bi = 2; }
            if (e3 > best) { best = e3; bi = 3; }
            ts0 = (bi == 0) ? tok : ts0;
            ts1 = (bi == 1) ? tok : ts1;
            ts2 = (bi == 2) ? tok : ts2;
            ts3 = (bi == 3) ? tok : ts3;
        }
        s_state[lane] = ts0 | (ts1 << 8) | (ts2 << 16) | (ts3 << 24);
    } else {
        // waves 1-3: stage qh1 + ebw as float4 (2112 vec4s / 192 threads)
        const float4* gq = (const float4*)t_qh1;   // 1056 vec4
        const float4* ge = (const float4*)t_ebw;   // 1056 vec4
        float4* sq = (float4*)s_qh1;
        float4* se = (float4*)s_ebw;
        for (int i = tid - 64; i < 2112; i += 192) {
            if (i < 1056) sq[i] = gq[i];
            else          se[i - 1056] = ge[i - 1056];
        }
        if (tid < 128) s_ebw[NTOK * 64 + (tid - 64)] = 0.0f;   // empty-slot row 66
    }
    __syncthreads();

    // head: per-lane-resident rh_w2 column, 16 elems per wave
    float w2c[64];                              // lane o holds rh_w2[:, o]
    #pragma unroll
    for (int k = 0; k < 64; ++k) w2c[k] = rh_w2[k * 64 + lane];
    const float rb2 = rh_b2[lane];

    for (int i = 0; i < 16; ++i) {
        const int e  = wv * 16 + i;
        const int bg = blockIdx.x * NB + e;
        const int qt = query_tok[bg];
        const unsigned st = (unsigned)s_state[e];
        const int u0 = st & 255, u1 = (st >> 8) & 255,
                  u2 = (st >> 16) & 255, u3 = st >> 24;
        float h1 = s_qh1[qt * 64 + lane]
                 + s_ebw[u0 * 64 + lane] + s_ebw[u1 * 64 + lane]
                 + s_ebw[u2 * 64 + lane] + s_ebw[u3 * 64 + lane];
        h1 = fmaxf(h1, 0.0f);

        float a0 = rb2, a1 = 0.0f, a2 = 0.0f, a3 = 0.0f;
        #pragma unroll
        for (int k = 0; k < 64; k += 4) {
            const float h0 = __uint_as_float(__builtin_amdgcn_readlane(__float_as_uint(h1), k));
            const float hA = __uint_as_float(__builtin_amdgcn_readlane(__float_as_uint(h1), k + 1));
            const float hB = __uint_as_float(__builtin_amdgcn_readlane(__float_as_uint(h1), k + 2));
            const float hC = __uint_as_float(__builtin_amdgcn_readlane(__float_as_uint(h1), k + 3));
            a0 = fmaf(h0, w2c[k],     a0);
            a1 = fmaf(hA, w2c[k + 1], a1);
            a2 = fmaf(hB, w2c[k + 2], a2);
            a3 = fmaf(hC, w2c[k + 3], a3);
        }
        out[bg * 64 + lane] = (a0 + a1) + (a2 + a3);
    }
}

extern "C" void kernel_launch(void* const* d_in, const int* in_sizes, int n_in,
                              void* d_out, int out_size, void* d_ws, size_t ws_size,
                              hipStream_t stream)
{
    const int*   seqs      = (const int*)  d_in[0];
    const int*   query_tok = (const int*)  d_in[1];
    const float* embed     = (const float*)d_in[2];
    const float* wg_w1     = (const float*)d_in[3];
    const float* wg_b1     = (const float*)d_in[4];
    const float* wg_w2     = (const float*)d_in[5];
    const float* wg_b2     = (const float*)d_in[6];
    const float* eg_w1     = (const float*)d_in[7];
    const float* eg_b1     = (const float*)d_in[8];
    const float* eg_w2     = (const float*)d_in[9];
    const float* eg_b2     = (const float*)d_in[10];
    const float* rh_w1     = (const float*)d_in[11];
    const float* rh_b1     = (const float*)d_in[12];
    const float* rh_w2     = (const float*)d_in[13];
    const float* rh_b2     = (const float*)d_in[14];
    float* out = (float*)d_out;
    const int B = in_sizes[1];   // 16384

    // workspace: t_EL padded to 4432 floats so t_qh1/t_ebw stay 16B-aligned
    float* t_EL  = (float*)d_ws;          // 66*67 used (4432 reserved)
    float* t_qh1 = t_EL + 4432;           // 66*64
    float* t_ebw = t_qh1 + 4224;          // 66*64

    k_tables<<<NTOK, 256, 0, stream>>>(embed, wg_w1, wg_b1, wg_w2, wg_b2,
                                       eg_w1, eg_b1, eg_w2, eg_b2,
                                       rh_w1, rh_b1, t_EL, t_qh1, t_ebw);
    k_main<<<B / NB, 256, 0, stream>>>(seqs, query_tok, t_EL, t_qh1, t_ebw,
                                       rh_w2, rh_b2, out);
}